// Round 7
// baseline (646.676 us; speedup 1.0000x reference)
//
#include <hip/hip_runtime.h>
#include <cstdint>

typedef _Float16 half8 __attribute__((ext_vector_type(8)));
typedef __attribute__((ext_vector_type(4))) float floatx4;
typedef unsigned int uint;

#define TSEQ 256
#define TDEC 180
#define NIN  6
#define GROWS 16
#define NGRP 2
#define NBLK (4096 / (GROWS * NGRP))   // 128 blocks, 2 independent groups each
#define RS0 104   // s0 row stride (halfs): cols 0..63 h0, 64..95 x|0, 96..103 pad
#define RS1 72    // s1 row stride

__device__ __forceinline__ floatx4 mfma16(half8 a, half8 b, floatx4 c) {
  return __builtin_amdgcn_mfma_f32_16x16x32_f16(a, b, c, 0, 0, 0);
}

__device__ __forceinline__ float sigm(float v) {
  return __builtin_amdgcn_rcpf(1.0f + __builtin_amdgcn_exp2f(-1.4426950408889634f * v));
}
__device__ __forceinline__ float tanh_fast(float v) {
  return 2.0f * __builtin_amdgcn_rcpf(1.0f + __builtin_amdgcn_exp2f(-2.8853900817779268f * v)) - 1.0f;
}

__device__ __forceinline__ half8 ldh8(const _Float16* p) { return *(const half8*)p; }

// single-term fp16: one 2-kt source -> 6 MFMAs into 3 gate accumulators
#define PASS2(F0, F1, r, z, g, W) do {                                  \
  r = mfma16(F0, W[0][0], r); z = mfma16(F0, W[1][0], z); g = mfma16(F0, W[2][0], g); \
  r = mfma16(F1, W[0][1], r); z = mfma16(F1, W[1][1], z); g = mfma16(F1, W[2][1], g); \
} while (0)

// 1-kt source (x slot) -> 3 MFMAs
#define PASS1(F0, r, z, g, W) do {                                      \
  r = mfma16(F0, W[0][0], r); z = mfma16(F0, W[1][0], z); g = mfma16(F0, W[2][0], g); \
} while (0)

__device__ __forceinline__ void pollge(const volatile uint* p4, uint need) {
  for (;;) {
    uint a = p4[0], b = p4[1], cc = p4[2], d = p4[3];
    uint mn = min(min(a, b), min(cc, d));
    if (mn >= need) break;
    __builtin_amdgcn_s_sleep(1);
  }
  asm volatile("" ::: "memory");   // no hoisting of data reads above the poll
}

__global__ void __launch_bounds__(1024, 4)
gru_persist(const float* __restrict__ x,
            const float* __restrict__ eWih0, const float* __restrict__ eWhh0,
            const float* __restrict__ ebih0, const float* __restrict__ ebhh0,
            const float* __restrict__ eWih1, const float* __restrict__ eWhh1,
            const float* __restrict__ ebih1, const float* __restrict__ ebhh1,
            const float* __restrict__ dWih0, const float* __restrict__ dWhh0,
            const float* __restrict__ dbih0, const float* __restrict__ dbhh0,
            const float* __restrict__ dWih1, const float* __restrict__ dWhh1,
            const float* __restrict__ dbih1, const float* __restrict__ dbhh1,
            const float* __restrict__ outW, const float* __restrict__ outB,
            float* __restrict__ out)
{
  __shared__ __align__(16) _Float16 s0[NGRP][2][16][RS0];
  __shared__ __align__(16) _Float16 s1[NGRP][2][16][RS1];
  __shared__ __align__(16) uint prog[NGRP][8];   // per group: [0..3]=A waves, [4..7]=B waves

  const int tid  = threadIdx.x;
  const int g    = tid >> 9;           // group 0/1 (independent 16-row problems)
  const int tid9 = tid & 511;
  const bool isA = tid9 < 256;         // A = layer0 waves, B = layer1 waves
  const int wvL  = (tid9 >> 6) & 3;
  const int lane = tid & 63;
  const int c    = lane & 15;
  const int q    = lane >> 4;
  const int u    = wvL * 16 + c;
  const long base = (long)blockIdx.x * (GROWS * NGRP) + g * GROWS;

  const volatile uint* aprog = (const volatile uint*)&prog[g][0];
  const volatile uint* bprog = (const volatile uint*)&prog[g][4];
  volatile uint* myslot = (volatile uint*)&prog[g][(isA ? 0 : 4) + wvL];

  for (int i = tid; i < NGRP * 2 * 16 * RS0; i += 1024) ((uint16_t*)s0)[i] = 0;
  for (int i = tid; i < NGRP * 2 * 16 * RS1; i += 1024) ((uint16_t*)s1)[i] = 0;
  if (tid < NGRP * 8) prog[tid >> 3][tid & 7] = 0;
  if (tid9 < GROWS * NIN) {  // x(0) -> s0[g][0]
    int m = tid9 / 6, i2 = tid9 - m * 6;
    s0[g][0][m][64 + i2] = (_Float16)x[(base + m) * (TSEQ * NIN) + i2];
  }

  half8 W1[3][2];   // A: Whh0 | B: Wih1
  half8 W2[3][2];   // A: [Wih0|0] (enc) / rank-1 fold (dec) | B: Whh1
  float hr[4] = {0, 0, 0, 0};

  auto loadW64 = [&](const float* W, half8 (&D)[3][2]) {
    #pragma unroll
    for (int s = 0; s < 3; s++) {
      const int n = (s * 4 + wvL) * 16 + c;
      #pragma unroll
      for (int kt = 0; kt < 2; kt++) {
        const int k0 = kt * 32 + q * 8;
        #pragma unroll
        for (int j = 0; j < 8; j++) D[s][kt][j] = (_Float16)W[n * 64 + k0 + j];
      }
    }
  };

  float cR, cZ, c3, c4;
  if (isA) {
    loadW64(eWhh0, W1);
    #pragma unroll
    for (int s = 0; s < 3; s++) {
      const int n = (s * 4 + wvL) * 16 + c;
      #pragma unroll
      for (int kt = 0; kt < 2; kt++)
        #pragma unroll
        for (int j = 0; j < 8; j++) {
          float v = (kt == 0 && q == 0 && j < NIN) ? eWih0[n * NIN + j] : 0.0f;
          W2[s][kt][j] = (_Float16)v;
        }
    }
    cR = ebih0[u] + ebhh0[u];
    cZ = ebih0[64 + u] + ebhh0[64 + u];
    c3 = ebhh0[128 + u];   // gh const (src1 = Whh0)
    c4 = ebih0[128 + u];   // gi const (src2 = x)
  } else {
    loadW64(eWih1, W1); loadW64(eWhh1, W2);
    cR = ebih1[u] + ebhh1[u];
    cZ = ebih1[64 + u] + ebhh1[64 + u];
    c3 = ebih1[128 + u];   // gi const (src1 = Wih1)
    c4 = ebhh1[128 + u];   // gh const (src2 = Whh1)
  }
  __syncthreads();   // last barrier: everything after uses the flag protocol

  if (isA) {
    // ---- x prefetch pipeline on wave A0 (per group), lanes 0..47, 2 slots, depth 2 ----
    const bool doX = (wvL == 0) && (lane < 48);
    const float *px0 = nullptr, *px1 = nullptr;
    int xo0 = 0, xo1 = 0; float xn0 = 0.f, xn1 = 0.f;
    if (doX) {
      int s0_ = lane, s1_ = lane + 48;
      int m0 = s0_ / 6, i0 = s0_ - m0 * 6, m1 = s1_ / 6, i1 = s1_ - m1 * 6;
      px0 = x + (base + m0) * (TSEQ * NIN) + i0;
      px1 = x + (base + m1) * (TSEQ * NIN) + i1;
      xo0 = m0 * RS0 + 64 + i0; xo1 = m1 * RS0 + 64 + i1;
      xn0 = px0[NIN]; xn1 = px1[NIN];   // x(1)
    }
    // ================= encoder =================
    for (int i = 0; i < TSEQ; i += 2) {
      #pragma unroll
      for (int h2 = 0; h2 < 2; h2++) {
        const int i_ = i + h2, p = h2, pn = h2 ^ 1;
        pollge(aprog, (uint)i_);                       // peers done step i_-1 (incl. x(i_))
        const half8 a0 = ldh8(&s0[g][p][c][q * 8]);
        const half8 a1 = ldh8(&s0[g][p][c][32 + q * 8]);
        const half8 xf = ldh8(&s0[g][p][c][64 + q * 8]);
        floatx4 aR = {cR, cR, cR, cR}, aZ = {cZ, cZ, cZ, cZ};
        floatx4 a3 = {c3, c3, c3, c3}, a4 = {c4, c4, c4, c4};
        PASS2(a0, a1, aR, aZ, a3, W1);                 // Whh0.h0 -> gh
        PASS1(xf, aR, aZ, a4, W2);                     // Wih0.x  -> gi
        pollge(bprog, (uint)(i_ > 0 ? i_ - 1 : 0));    // WAR: B consumed s0[pn] generation-2
        if (doX && i_ + 1 < TSEQ) {
          ((_Float16*)s0[g][pn])[xo0] = (_Float16)xn0;
          ((_Float16*)s0[g][pn])[xo1] = (_Float16)xn1;
          if (i_ + 2 < TSEQ) { xn0 = px0[(i_ + 2) * NIN]; xn1 = px1[(i_ + 2) * NIN]; }
        }
        #pragma unroll
        for (int r4 = 0; r4 < 4; r4++) {
          const float gr = sigm(aR[r4]);
          const float gz = sigm(aZ[r4]);
          const float nn = tanh_fast(a4[r4] + gr * a3[r4]);
          const float hn = nn + gz * (hr[r4] - nn);
          hr[r4] = hn;
          s0[g][pn][q * 4 + r4][u] = (_Float16)hn;
        }
        asm volatile("s_waitcnt lgkmcnt(0)" ::: "memory");
        *myslot = (uint)(i_ + 1);
      }
    }
    // ================= decoder weights (fold) =================
    loadW64(dWhh0, W1);
    const float ob = outB[0];
    #pragma unroll
    for (int s = 0; s < 3; s++) {
      const int n = (s * 4 + wvL) * 16 + c;
      const float wd = dWih0[n];
      #pragma unroll
      for (int kt = 0; kt < 2; kt++) {
        const int k0 = kt * 32 + q * 8;
        #pragma unroll
        for (int j = 0; j < 8; j++) W2[s][kt][j] = (_Float16)(wd * outW[k0 + j]);
      }
    }
    const float bR0 = dbih0[u] + dbhh0[u];
    const float bZ0 = dbih0[64 + u] + dbhh0[64 + u];
    const float b30 = dbhh0[128 + u];
    const float b40 = dbih0[128 + u];
    cR = bR0 + dWih0[u] * ob;
    cZ = bZ0 + dWih0[64 + u] * ob;
    c3 = b30;
    c4 = b40 + dWih0[128 + u] * ob;
    // ================= decoder =================
    for (int i = TSEQ; i < TSEQ + TDEC; i += 2) {
      #pragma unroll
      for (int h2 = 0; h2 < 2; h2++) {
        const int i_ = i + h2, p = h2, pn = h2 ^ 1;
        const bool first = (i_ == TSEQ);
        pollge(aprog, (uint)i_);
        const half8 a0 = ldh8(&s0[g][p][c][q * 8]);
        const half8 a1 = ldh8(&s0[g][p][c][32 + q * 8]);
        const float vR = first ? bR0 : cR, vZ = first ? bZ0 : cZ, v4 = first ? b40 : c4;
        floatx4 aR = {vR, vR, vR, vR}, aZ = {vZ, vZ, vZ, vZ};
        floatx4 a3 = {c3, c3, c3, c3}, a4 = {v4, v4, v4, v4};
        PASS2(a0, a1, aR, aZ, a3, W1);                 // Whh0.h0 -> gh
        pollge(bprog, (uint)(first ? i_ - 1 : i_));
        if (!first) {   // rank-1 head fold: W'.h1(d-1) -> r,z,gi
          const half8 b0 = ldh8(&s1[g][p][c][q * 8]);
          const half8 b1 = ldh8(&s1[g][p][c][32 + q * 8]);
          PASS2(b0, b1, aR, aZ, a4, W2);
        }
        #pragma unroll
        for (int r4 = 0; r4 < 4; r4++) {
          const float gr = sigm(aR[r4]);
          const float gz = sigm(aZ[r4]);
          const float nn = tanh_fast(a4[r4] + gr * a3[r4]);
          const float hn = nn + gz * (hr[r4] - nn);
          hr[r4] = hn;
          s0[g][pn][q * 4 + r4][u] = (_Float16)hn;
        }
        asm volatile("s_waitcnt lgkmcnt(0)" ::: "memory");
        *myslot = (uint)(i_ + 1);
      }
    }
  } else {
    // =========================== group B: layer 1 ===========================
    const float ob = outB[0];
    float wk[2][8];
    #pragma unroll
    for (int kt = 0; kt < 2; kt++)
      #pragma unroll
      for (int j = 0; j < 8; j++) wk[kt][j] = outW[kt * 32 + q * 8 + j];

    for (int i = 0; i < TSEQ; i += 2) {
      #pragma unroll
      for (int h2 = 0; h2 < 2; h2++) {
        const int i_ = i + h2, p = h2, pn = h2 ^ 1;
        pollge(bprog, (uint)i_);                       // peers' h1(i_-1)
        const half8 f0 = ldh8(&s1[g][p][c][q * 8]);
        const half8 f1 = ldh8(&s1[g][p][c][32 + q * 8]);
        floatx4 aR = {cR, cR, cR, cR}, aZ = {cZ, cZ, cZ, cZ};
        floatx4 a3 = {c3, c3, c3, c3}, a4 = {c4, c4, c4, c4};
        PASS2(f0, f1, aR, aZ, a4, W2);                 // Whh1.h1 -> gh
        pollge(aprog, (uint)(i_ + 1));                 // h0(i_) ready
        const half8 g0 = ldh8(&s0[g][pn][c][q * 8]);
        const half8 g1 = ldh8(&s0[g][pn][c][32 + q * 8]);
        PASS2(g0, g1, aR, aZ, a3, W1);                 // Wih1.h0 -> gi
        #pragma unroll
        for (int r4 = 0; r4 < 4; r4++) {
          const float gr = sigm(aR[r4]);
          const float gz = sigm(aZ[r4]);
          const float nn = tanh_fast(a3[r4] + gr * a4[r4]);
          const float hn = nn + gz * (hr[r4] - nn);
          hr[r4] = hn;
          s1[g][pn][q * 4 + r4][u] = (_Float16)hn;
        }
        asm volatile("s_waitcnt lgkmcnt(0)" ::: "memory");
        *myslot = (uint)(i_ + 1);
      }
    }
    loadW64(dWih1, W1); loadW64(dWhh1, W2);
    cR = dbih1[u] + dbhh1[u];
    cZ = dbih1[64 + u] + dbhh1[64 + u];
    c3 = dbih1[128 + u]; c4 = dbhh1[128 + u];
    for (int i = TSEQ; i < TSEQ + TDEC; i += 2) {
      #pragma unroll
      for (int h2 = 0; h2 < 2; h2++) {
        const int i_ = i + h2, p = h2, pn = h2 ^ 1;
        pollge(bprog, (uint)i_);
        const half8 f0 = ldh8(&s1[g][p][c][q * 8]);
        const half8 f1 = ldh8(&s1[g][p][c][32 + q * 8]);
        floatx4 aR = {cR, cR, cR, cR}, aZ = {cZ, cZ, cZ, cZ};
        floatx4 a3 = {c3, c3, c3, c3}, a4 = {c4, c4, c4, c4};
        PASS2(f0, f1, aR, aZ, a4, W2);                 // Whh1.h1 -> gh
        if (wvL == 0 && i_ > TSEQ) {   // head: cv(d) from h1(i_-1) fragments (off critical path)
          float cv = 0.0f;
          #pragma unroll
          for (int j = 0; j < 8; j++) {
            cv = fmaf((float)f0[j], wk[0][j], cv);
            cv = fmaf((float)f1[j], wk[1][j], cv);
          }
          cv += __shfl_xor(cv, 16);
          cv += __shfl_xor(cv, 32);
          if (lane < 16) out[(base + lane) * TDEC + (i_ - TSEQ - 1)] = cv + ob;
        }
        pollge(aprog, (uint)(i_ + 1));
        const half8 g0 = ldh8(&s0[g][pn][c][q * 8]);
        const half8 g1 = ldh8(&s0[g][pn][c][32 + q * 8]);
        PASS2(g0, g1, aR, aZ, a3, W1);                 // Wih1.h0 -> gi
        #pragma unroll
        for (int r4 = 0; r4 < 4; r4++) {
          const float gr = sigm(aR[r4]);
          const float gz = sigm(aZ[r4]);
          const float nn = tanh_fast(a3[r4] + gr * a4[r4]);
          const float hn = nn + gz * (hr[r4] - nn);
          hr[r4] = hn;
          s1[g][pn][q * 4 + r4][u] = (_Float16)hn;
        }
        asm volatile("s_waitcnt lgkmcnt(0)" ::: "memory");
        *myslot = (uint)(i_ + 1);
      }
    }
    // final head value: cv(179) from h1(435) in s1[g][0]
    if (wvL == 0) {
      pollge(bprog, (uint)(TSEQ + TDEC));
      const half8 f0 = ldh8(&s1[g][0][c][q * 8]);
      const half8 f1 = ldh8(&s1[g][0][c][32 + q * 8]);
      float cv = 0.0f;
      #pragma unroll
      for (int j = 0; j < 8; j++) {
        cv = fmaf((float)f0[j], wk[0][j], cv);
        cv = fmaf((float)f1[j], wk[1][j], cv);
      }
      cv += __shfl_xor(cv, 16);
      cv += __shfl_xor(cv, 32);
      if (lane < 16) out[(base + lane) * TDEC + (TDEC - 1)] = cv + ob;
    }
  }
}

extern "C" void kernel_launch(void* const* d_in, const int* in_sizes, int n_in,
                              void* d_out, int out_size, void* d_ws, size_t ws_size,
                              hipStream_t stream) {
  (void)in_sizes; (void)n_in; (void)d_ws; (void)ws_size; (void)out_size;
  const float* x     = (const float*)d_in[0];
  const float* eWih0 = (const float*)d_in[1];
  const float* eWhh0 = (const float*)d_in[2];
  const float* ebih0 = (const float*)d_in[3];
  const float* ebhh0 = (const float*)d_in[4];
  const float* eWih1 = (const float*)d_in[5];
  const float* eWhh1 = (const float*)d_in[6];
  const float* ebih1 = (const float*)d_in[7];
  const float* ebhh1 = (const float*)d_in[8];
  const float* dWih0 = (const float*)d_in[9];
  const float* dWhh0 = (const float*)d_in[10];
  const float* dbih0 = (const float*)d_in[11];
  const float* dbhh0 = (const float*)d_in[12];
  const float* dWih1 = (const float*)d_in[13];
  const float* dWhh1 = (const float*)d_in[14];
  const float* dbih1 = (const float*)d_in[15];
  const float* dbhh1 = (const float*)d_in[16];
  const float* outW  = (const float*)d_in[17];
  const float* outB  = (const float*)d_in[18];
  hipLaunchKernelGGL(gru_persist, dim3(NBLK), dim3(1024), 0, stream,
                     x, eWih0, eWhh0, ebih0, ebhh0, eWih1, eWhh1, ebih1, ebhh1,
                     dWih0, dWhh0, dbih0, dbhh0, dWih1, dWhh1, dbih1, dbhh1,
                     outW, outB, (float*)d_out);
}

// Round 9
// 410.986 us; speedup vs baseline: 1.5735x; 1.5735x over previous
//
#include <hip/hip_runtime.h>
#include <cstdint>

typedef _Float16 half8 __attribute__((ext_vector_type(8)));
typedef __attribute__((ext_vector_type(4))) float floatx4;
typedef unsigned int uint;

#define TSEQ 256
#define TDEC 180
#define NIN  6
#define GROWS 16
#define NBLK (4096 / GROWS)
#define RS0 104   // s0 row stride (halfs): cols 0..63 h0, 64..95 x|0, 96..103 pad
#define RS1 72    // s1 row stride

__device__ __forceinline__ floatx4 mfma16(half8 a, half8 b, floatx4 c) {
  return __builtin_amdgcn_mfma_f32_16x16x32_f16(a, b, c, 0, 0, 0);
}

__device__ __forceinline__ float sigm(float v) {
  return __builtin_amdgcn_rcpf(1.0f + __builtin_amdgcn_exp2f(-1.4426950408889634f * v));
}
__device__ __forceinline__ float tanh_fast(float v) {
  return 2.0f * __builtin_amdgcn_rcpf(1.0f + __builtin_amdgcn_exp2f(-2.8853900817779268f * v)) - 1.0f;
}

__device__ __forceinline__ half8 ldh8(const _Float16* p) { return *(const half8*)p; }

// single-term fp16: one 2-kt source -> 6 MFMAs into 3 gate accumulators
#define PASS2(F0, F1, r, z, g, W) do {                                  \
  r = mfma16(F0, W[0][0], r); z = mfma16(F0, W[1][0], z); g = mfma16(F0, W[2][0], g); \
  r = mfma16(F1, W[0][1], r); z = mfma16(F1, W[1][1], z); g = mfma16(F1, W[2][1], g); \
} while (0)

// 1-kt source (x slot) -> 3 MFMAs
#define PASS1(F0, r, z, g, W) do {                                      \
  r = mfma16(F0, W[0][0], r); z = mfma16(F0, W[1][0], z); g = mfma16(F0, W[2][0], g); \
} while (0)

// sum-counter poll: all 4 waves of a group finished >= n  <=>  sum >= 4n
// (publish is +1 per wave — lane-0-gated atomic; compensation is provably impossible
//  because each wave gates its own step on its group sum)
__device__ __forceinline__ void pollge1(const volatile uint* p, uint need4) {
  for (;;) {
    if (*p >= need4) break;
    __builtin_amdgcn_s_sleep(1);
  }
  asm volatile("" ::: "memory");   // no hoisting of data reads above the poll
}

__global__ void __launch_bounds__(512, 2)
gru_persist(const float* __restrict__ x,
            const float* __restrict__ eWih0, const float* __restrict__ eWhh0,
            const float* __restrict__ ebih0, const float* __restrict__ ebhh0,
            const float* __restrict__ eWih1, const float* __restrict__ eWhh1,
            const float* __restrict__ ebih1, const float* __restrict__ ebhh1,
            const float* __restrict__ dWih0, const float* __restrict__ dWhh0,
            const float* __restrict__ dbih0, const float* __restrict__ dbhh0,
            const float* __restrict__ dWih1, const float* __restrict__ dWhh1,
            const float* __restrict__ dbih1, const float* __restrict__ dbhh1,
            const float* __restrict__ outW, const float* __restrict__ outB,
            float* __restrict__ out)
{
  __shared__ __align__(16) _Float16 s0[2][16][RS0];
  __shared__ __align__(16) _Float16 s1[2][16][RS1];
  __shared__ __align__(16) uint prog[16];   // prog[0]=A-sum, prog[8]=B-sum (separate banks)

  const int tid  = threadIdx.x;
  const bool isA = tid < 256;          // A = layer0 waves, B = layer1 waves
  const int wvL  = (tid >> 6) & 3;
  const int lane = tid & 63;
  const int c    = lane & 15;
  const int q    = lane >> 4;
  const int u    = wvL * 16 + c;
  const long base = (long)blockIdx.x * GROWS;

  const volatile uint* asum = (const volatile uint*)&prog[0];
  const volatile uint* bsum = (const volatile uint*)&prog[8];
  uint* mysum = (uint*)&prog[isA ? 0 : 8];

  for (int i = tid; i < 2 * 16 * RS0; i += 512) ((uint16_t*)s0)[i] = 0;
  for (int i = tid; i < 2 * 16 * RS1; i += 512) ((uint16_t*)s1)[i] = 0;
  if (tid < 16) prog[tid] = 0;
  if (tid < GROWS * NIN) {  // x(0) -> s0[0]
    int m = tid / 6, i2 = tid - m * 6;
    s0[0][m][64 + i2] = (_Float16)x[(base + m) * (TSEQ * NIN) + i2];
  }

  half8 W1[3][2];   // A: Whh0 | B: Wih1
  half8 W2[3][2];   // A: [Wih0|0] (enc) / rank-1 fold (dec) | B: Whh1
  float hr[4] = {0, 0, 0, 0};

  auto loadW64 = [&](const float* W, half8 (&D)[3][2]) {
    #pragma unroll
    for (int s = 0; s < 3; s++) {
      const int n = (s * 4 + wvL) * 16 + c;
      #pragma unroll
      for (int kt = 0; kt < 2; kt++) {
        const int k0 = kt * 32 + q * 8;
        #pragma unroll
        for (int j = 0; j < 8; j++) D[s][kt][j] = (_Float16)W[n * 64 + k0 + j];
      }
    }
  };

  float cR, cZ, c3, c4;
  if (isA) {
    loadW64(eWhh0, W1);
    #pragma unroll
    for (int s = 0; s < 3; s++) {
      const int n = (s * 4 + wvL) * 16 + c;
      #pragma unroll
      for (int kt = 0; kt < 2; kt++)
        #pragma unroll
        for (int j = 0; j < 8; j++) {
          float v = (kt == 0 && q == 0 && j < NIN) ? eWih0[n * NIN + j] : 0.0f;
          W2[s][kt][j] = (_Float16)v;
        }
    }
    cR = ebih0[u] + ebhh0[u];
    cZ = ebih0[64 + u] + ebhh0[64 + u];
    c3 = ebhh0[128 + u];   // gh const (src1 = Whh0)
    c4 = ebih0[128 + u];   // gi const (src2 = x)
  } else {
    loadW64(eWih1, W1); loadW64(eWhh1, W2);
    cR = ebih1[u] + ebhh1[u];
    cZ = ebih1[64 + u] + ebhh1[64 + u];
    c3 = ebih1[128 + u];   // gi const (src1 = Wih1)
    c4 = ebhh1[128 + u];   // gh const (src2 = Whh1)
  }
  __syncthreads();   // last barrier: everything after uses the flag protocol

  if (isA) {
    // ---- x prefetch pipeline on wave A0, lanes 0..47, 2 slots each, depth 2 ----
    const bool doX = (wvL == 0) && (lane < 48);
    const float *px0 = nullptr, *px1 = nullptr;
    int xo0 = 0, xo1 = 0; float xn0 = 0.f, xn1 = 0.f;
    if (doX) {
      int s0_ = lane, s1_ = lane + 48;
      int m0 = s0_ / 6, i0 = s0_ - m0 * 6, m1 = s1_ / 6, i1 = s1_ - m1 * 6;
      px0 = x + (base + m0) * (TSEQ * NIN) + i0;
      px1 = x + (base + m1) * (TSEQ * NIN) + i1;
      xo0 = m0 * RS0 + 64 + i0; xo1 = m1 * RS0 + 64 + i1;
      xn0 = px0[NIN]; xn1 = px1[NIN];   // x(1)
    }
    // ================= encoder =================
    for (int i = 0; i < TSEQ; i += 2) {
      #pragma unroll
      for (int h2 = 0; h2 < 2; h2++) {
        const int i_ = i + h2, p = h2, pn = h2 ^ 1;
        pollge1(asum, 4u * (uint)i_);                  // peers done step i_-1 (incl. x(i_))
        const half8 a0 = ldh8(&s0[p][c][q * 8]);
        const half8 a1 = ldh8(&s0[p][c][32 + q * 8]);
        const half8 xf = ldh8(&s0[p][c][64 + q * 8]);
        floatx4 aR = {cR, cR, cR, cR}, aZ = {cZ, cZ, cZ, cZ};
        floatx4 a3 = {c3, c3, c3, c3}, a4 = {c4, c4, c4, c4};
        PASS2(a0, a1, aR, aZ, a3, W1);                 // Whh0.h0 -> gh
        PASS1(xf, aR, aZ, a4, W2);                     // Wih0.x  -> gi
        pollge1(bsum, 4u * (uint)(i_ > 0 ? i_ - 1 : 0));  // WAR: B consumed s0[pn] gen-2
        if (doX && i_ + 1 < TSEQ) {
          ((_Float16*)s0[pn])[xo0] = (_Float16)xn0;
          ((_Float16*)s0[pn])[xo1] = (_Float16)xn1;
          if (i_ + 2 < TSEQ) { xn0 = px0[(i_ + 2) * NIN]; xn1 = px1[(i_ + 2) * NIN]; }
        }
        #pragma unroll
        for (int r4 = 0; r4 < 4; r4++) {
          const float gr = sigm(aR[r4]);
          const float gz = sigm(aZ[r4]);
          const float nn = tanh_fast(a4[r4] + gr * a3[r4]);
          const float hn = nn + gz * (hr[r4] - nn);
          hr[r4] = hn;
          s0[pn][q * 4 + r4][u] = (_Float16)hn;
        }
        asm volatile("s_waitcnt lgkmcnt(0)" ::: "memory");
        if (lane == 0) atomicAdd(mysum, 1u);           // +1 per wave (lane-0 gated)
      }
    }
    // ================= decoder weights (fold) =================
    loadW64(dWhh0, W1);
    const float ob = outB[0];
    #pragma unroll
    for (int s = 0; s < 3; s++) {
      const int n = (s * 4 + wvL) * 16 + c;
      const float wd = dWih0[n];
      #pragma unroll
      for (int kt = 0; kt < 2; kt++) {
        const int k0 = kt * 32 + q * 8;
        #pragma unroll
        for (int j = 0; j < 8; j++) W2[s][kt][j] = (_Float16)(wd * outW[k0 + j]);
      }
    }
    const float bR0 = dbih0[u] + dbhh0[u];
    const float bZ0 = dbih0[64 + u] + dbhh0[64 + u];
    const float b30 = dbhh0[128 + u];
    const float b40 = dbih0[128 + u];
    cR = bR0 + dWih0[u] * ob;
    cZ = bZ0 + dWih0[64 + u] * ob;
    c3 = b30;
    c4 = b40 + dWih0[128 + u] * ob;
    // ================= decoder =================
    for (int i = TSEQ; i < TSEQ + TDEC; i += 2) {
      #pragma unroll
      for (int h2 = 0; h2 < 2; h2++) {
        const int i_ = i + h2, p = h2, pn = h2 ^ 1;
        const bool first = (i_ == TSEQ);
        pollge1(asum, 4u * (uint)i_);
        const half8 a0 = ldh8(&s0[p][c][q * 8]);
        const half8 a1 = ldh8(&s0[p][c][32 + q * 8]);
        const float vR = first ? bR0 : cR, vZ = first ? bZ0 : cZ, v4 = first ? b40 : c4;
        floatx4 aR = {vR, vR, vR, vR}, aZ = {vZ, vZ, vZ, vZ};
        floatx4 a3 = {c3, c3, c3, c3}, a4 = {v4, v4, v4, v4};
        PASS2(a0, a1, aR, aZ, a3, W1);                 // Whh0.h0 -> gh
        pollge1(bsum, 4u * (uint)(first ? i_ - 1 : i_));
        if (!first) {   // rank-1 head fold: W'.h1(d-1) -> r,z,gi
          const half8 b0 = ldh8(&s1[p][c][q * 8]);
          const half8 b1 = ldh8(&s1[p][c][32 + q * 8]);
          PASS2(b0, b1, aR, aZ, a4, W2);
        }
        #pragma unroll
        for (int r4 = 0; r4 < 4; r4++) {
          const float gr = sigm(aR[r4]);
          const float gz = sigm(aZ[r4]);
          const float nn = tanh_fast(a4[r4] + gr * a3[r4]);
          const float hn = nn + gz * (hr[r4] - nn);
          hr[r4] = hn;
          s0[pn][q * 4 + r4][u] = (_Float16)hn;
        }
        asm volatile("s_waitcnt lgkmcnt(0)" ::: "memory");
        if (lane == 0) atomicAdd(mysum, 1u);
      }
    }
  } else {
    // =========================== group B: layer 1 ===========================
    const float ob = outB[0];
    float wk[2][8];
    #pragma unroll
    for (int kt = 0; kt < 2; kt++)
      #pragma unroll
      for (int j = 0; j < 8; j++) wk[kt][j] = outW[kt * 32 + q * 8 + j];

    for (int i = 0; i < TSEQ; i += 2) {
      #pragma unroll
      for (int h2 = 0; h2 < 2; h2++) {
        const int i_ = i + h2, p = h2, pn = h2 ^ 1;
        pollge1(bsum, 4u * (uint)i_);                  // peers' h1(i_-1)
        const half8 f0 = ldh8(&s1[p][c][q * 8]);
        const half8 f1 = ldh8(&s1[p][c][32 + q * 8]);
        floatx4 aR = {cR, cR, cR, cR}, aZ = {cZ, cZ, cZ, cZ};
        floatx4 a3 = {c3, c3, c3, c3}, a4 = {c4, c4, c4, c4};
        PASS2(f0, f1, aR, aZ, a4, W2);                 // Whh1.h1 -> gh
        pollge1(asum, 4u * (uint)(i_ + 1));            // h0(i_) ready
        const half8 g0 = ldh8(&s0[pn][c][q * 8]);
        const half8 g1 = ldh8(&s0[pn][c][32 + q * 8]);
        PASS2(g0, g1, aR, aZ, a3, W1);                 // Wih1.h0 -> gi
        #pragma unroll
        for (int r4 = 0; r4 < 4; r4++) {
          const float gr = sigm(aR[r4]);
          const float gz = sigm(aZ[r4]);
          const float nn = tanh_fast(a3[r4] + gr * a4[r4]);
          const float hn = nn + gz * (hr[r4] - nn);
          hr[r4] = hn;
          s1[pn][q * 4 + r4][u] = (_Float16)hn;
        }
        asm volatile("s_waitcnt lgkmcnt(0)" ::: "memory");
        if (lane == 0) atomicAdd(mysum, 1u);
      }
    }
    loadW64(dWih1, W1); loadW64(dWhh1, W2);
    cR = dbih1[u] + dbhh1[u];
    cZ = dbih1[64 + u] + dbhh1[64 + u];
    c3 = dbih1[128 + u]; c4 = dbhh1[128 + u];
    for (int i = TSEQ; i < TSEQ + TDEC; i += 2) {
      #pragma unroll
      for (int h2 = 0; h2 < 2; h2++) {
        const int i_ = i + h2, p = h2, pn = h2 ^ 1;
        pollge1(bsum, 4u * (uint)i_);
        const half8 f0 = ldh8(&s1[p][c][q * 8]);
        const half8 f1 = ldh8(&s1[p][c][32 + q * 8]);
        floatx4 aR = {cR, cR, cR, cR}, aZ = {cZ, cZ, cZ, cZ};
        floatx4 a3 = {c3, c3, c3, c3}, a4 = {c4, c4, c4, c4};
        PASS2(f0, f1, aR, aZ, a4, W2);                 // Whh1.h1 -> gh
        if (wvL == 0 && i_ > TSEQ) {   // head: cv(d) from h1(i_-1) fragments (off critical path)
          float cv = 0.0f;
          #pragma unroll
          for (int j = 0; j < 8; j++) {
            cv = fmaf((float)f0[j], wk[0][j], cv);
            cv = fmaf((float)f1[j], wk[1][j], cv);
          }
          cv += __shfl_xor(cv, 16);
          cv += __shfl_xor(cv, 32);
          if (lane < 16) out[(base + lane) * TDEC + (i_ - TSEQ - 1)] = cv + ob;
        }
        pollge1(asum, 4u * (uint)(i_ + 1));
        const half8 g0 = ldh8(&s0[pn][c][q * 8]);
        const half8 g1 = ldh8(&s0[pn][c][32 + q * 8]);
        PASS2(g0, g1, aR, aZ, a3, W1);                 // Wih1.h0 -> gi
        #pragma unroll
        for (int r4 = 0; r4 < 4; r4++) {
          const float gr = sigm(aR[r4]);
          const float gz = sigm(aZ[r4]);
          const float nn = tanh_fast(a3[r4] + gr * a4[r4]);
          const float hn = nn + gz * (hr[r4] - nn);
          hr[r4] = hn;
          s1[pn][q * 4 + r4][u] = (_Float16)hn;
        }
        asm volatile("s_waitcnt lgkmcnt(0)" ::: "memory");
        if (lane == 0) atomicAdd(mysum, 1u);
      }
    }
    // final head value: cv(179) from h1(435) in s1[0]
    if (wvL == 0) {
      pollge1(bsum, 4u * (uint)(TSEQ + TDEC));
      const half8 f0 = ldh8(&s1[0][c][q * 8]);
      const half8 f1 = ldh8(&s1[0][c][32 + q * 8]);
      float cv = 0.0f;
      #pragma unroll
      for (int j = 0; j < 8; j++) {
        cv = fmaf((float)f0[j], wk[0][j], cv);
        cv = fmaf((float)f1[j], wk[1][j], cv);
      }
      cv += __shfl_xor(cv, 16);
      cv += __shfl_xor(cv, 32);
      if (lane < 16) out[(base + lane) * TDEC + (TDEC - 1)] = cv + ob;
    }
  }
}

extern "C" void kernel_launch(void* const* d_in, const int* in_sizes, int n_in,
                              void* d_out, int out_size, void* d_ws, size_t ws_size,
                              hipStream_t stream) {
  (void)in_sizes; (void)n_in; (void)d_ws; (void)ws_size; (void)out_size;
  const float* x     = (const float*)d_in[0];
  const float* eWih0 = (const float*)d_in[1];
  const float* eWhh0 = (const float*)d_in[2];
  const float* ebih0 = (const float*)d_in[3];
  const float* ebhh0 = (const float*)d_in[4];
  const float* eWih1 = (const float*)d_in[5];
  const float* eWhh1 = (const float*)d_in[6];
  const float* ebih1 = (const float*)d_in[7];
  const float* ebhh1 = (const float*)d_in[8];
  const float* dWih0 = (const float*)d_in[9];
  const float* dWhh0 = (const float*)d_in[10];
  const float* dbih0 = (const float*)d_in[11];
  const float* dbhh0 = (const float*)d_in[12];
  const float* dWih1 = (const float*)d_in[13];
  const float* dWhh1 = (const float*)d_in[14];
  const float* dbih1 = (const float*)d_in[15];
  const float* dbhh1 = (const float*)d_in[16];
  const float* outW  = (const float*)d_in[17];
  const float* outB  = (const float*)d_in[18];
  hipLaunchKernelGGL(gru_persist, dim3(NBLK), dim3(512), 0, stream,
                     x, eWih0, eWhh0, ebih0, ebhh0, eWih1, eWhh1, ebih1, ebhh1,
                     dWih0, dWhh0, dbih0, dbhh0, dWih1, dWhh1, dbih1, dbhh1,
                     outW, outB, (float*)d_out);
}

// Round 10
// 392.663 us; speedup vs baseline: 1.6469x; 1.0467x over previous
//
#include <hip/hip_runtime.h>
#include <cstdint>

typedef _Float16 half8 __attribute__((ext_vector_type(8)));
typedef __attribute__((ext_vector_type(4))) float floatx4;
typedef unsigned int uint;

#define TSEQ 256
#define TDEC 180
#define NIN  6
#define GROWS 16
#define NBLK (4096 / GROWS)
#define RS0 104   // s0 row stride (halfs): cols 0..63 h0, 64..95 x|0, 96..103 pad
#define RS1 72    // s1 row stride
#define L2E 1.4426950408889634f

__device__ __forceinline__ floatx4 mfma16(half8 a, half8 b, floatx4 c) {
  return __builtin_amdgcn_mfma_f32_16x16x32_f16(a, b, c, 0, 0, 0);
}

// pre-scaled transcendentals: inputs already carry log2e (sigm) / 2*log2e (tanh)
__device__ __forceinline__ float sigm2(float v) {
  return __builtin_amdgcn_rcpf(1.0f + __builtin_amdgcn_exp2f(-v));
}
__device__ __forceinline__ float tanh2(float v) {
  return fmaf(2.0f, __builtin_amdgcn_rcpf(1.0f + __builtin_amdgcn_exp2f(-v)), -1.0f);
}

__device__ __forceinline__ half8 ldh8(const _Float16* p) { return *(const half8*)p; }

// 2-kt pass, all three accumulators initialized from persistent bias quads (MFMA C != D)
#define PASS2_I3(F0, F1, r, z, g, W, QR, QZ, QG) do {                   \
  r = mfma16(F0, W[0][0], QR); z = mfma16(F0, W[1][0], QZ); g = mfma16(F0, W[2][0], QG); \
  r = mfma16(F1, W[0][1], r);  z = mfma16(F1, W[1][1], z);  g = mfma16(F1, W[2][1], g);  \
} while (0)

// 2-kt pass, r/z accumulate, g initialized from quad
#define PASS2_A2I1(F0, F1, r, z, g, W, QG) do {                         \
  r = mfma16(F0, W[0][0], r); z = mfma16(F0, W[1][0], z); g = mfma16(F0, W[2][0], QG); \
  r = mfma16(F1, W[0][1], r); z = mfma16(F1, W[1][1], z); g = mfma16(F1, W[2][1], g);  \
} while (0)

// 1-kt pass (x slot): r/z accumulate, g initialized from quad
#define PASS1_A2I1(F0, r, z, g, W, QG) do {                             \
  r = mfma16(F0, W[0][0], r); z = mfma16(F0, W[1][0], z); g = mfma16(F0, W[2][0], QG); \
} while (0)

// sum-counter poll: all 4 waves of a group finished >= n  <=>  sum >= 4n
__device__ __forceinline__ void pollge1(const volatile uint* p, uint need4) {
  for (;;) {
    if (*p >= need4) break;
    __builtin_amdgcn_s_sleep(1);
  }
  asm volatile("" ::: "memory");   // no hoisting of data reads above the poll
}

// publish: DS ops of one wave execute in order in the LDS pipe, so the ds_add cannot
// pass the preceding ds_writes — compiler fence only, no s_waitcnt drain.
#define PUBLISH() do { asm volatile("" ::: "memory"); if (lane == 0) atomicAdd(mysum, 1u); } while (0)

__global__ void __launch_bounds__(512, 2)
gru_persist(const float* __restrict__ x,
            const float* __restrict__ eWih0, const float* __restrict__ eWhh0,
            const float* __restrict__ ebih0, const float* __restrict__ ebhh0,
            const float* __restrict__ eWih1, const float* __restrict__ eWhh1,
            const float* __restrict__ ebih1, const float* __restrict__ ebhh1,
            const float* __restrict__ dWih0, const float* __restrict__ dWhh0,
            const float* __restrict__ dbih0, const float* __restrict__ dbhh0,
            const float* __restrict__ dWih1, const float* __restrict__ dWhh1,
            const float* __restrict__ dbih1, const float* __restrict__ dbhh1,
            const float* __restrict__ outW, const float* __restrict__ outB,
            float* __restrict__ out)
{
  __shared__ __align__(16) _Float16 s0[2][16][RS0];
  __shared__ __align__(16) _Float16 s1[2][16][RS1];
  __shared__ __align__(16) uint prog[16];   // prog[0]=A-sum, prog[8]=B-sum

  const int tid  = threadIdx.x;
  const bool isA = tid < 256;          // A = layer0 waves, B = layer1 waves
  const int wvL  = (tid >> 6) & 3;
  const int lane = tid & 63;
  const int c    = lane & 15;
  const int q    = lane >> 4;
  const int u    = wvL * 16 + c;
  const long base = (long)blockIdx.x * GROWS;

  const volatile uint* asum = (const volatile uint*)&prog[0];
  const volatile uint* bsum = (const volatile uint*)&prog[8];
  uint* mysum = (uint*)&prog[isA ? 0 : 8];

  for (int i = tid; i < 2 * 16 * RS0; i += 512) ((uint16_t*)s0)[i] = 0;
  for (int i = tid; i < 2 * 16 * RS1; i += 512) ((uint16_t*)s1)[i] = 0;
  if (tid < 16) prog[tid] = 0;
  if (tid < GROWS * NIN) {  // x(0) -> s0[0]
    int m = tid / 6, i2 = tid - m * 6;
    s0[0][m][64 + i2] = (_Float16)x[(base + m) * (TSEQ * NIN) + i2];
  }

  half8 W1[3][2];   // A: Whh0 | B: Wih1      (rows pre-scaled per gate slot)
  half8 W2[3][2];   // A: [Wih0|0] / fold | B: Whh1
  float hr[4] = {0, 0, 0, 0};
  const float SC[3] = {L2E, L2E, 2.0f * L2E};   // r, z, n row scales

  auto loadW64 = [&](const float* W, half8 (&D)[3][2]) {
    #pragma unroll
    for (int s = 0; s < 3; s++) {
      const int n = (s * 4 + wvL) * 16 + c;
      #pragma unroll
      for (int kt = 0; kt < 2; kt++) {
        const int k0 = kt * 32 + q * 8;
        #pragma unroll
        for (int j = 0; j < 8; j++) D[s][kt][j] = (_Float16)(SC[s] * W[n * 64 + k0 + j]);
      }
    }
  };

  float cR, cZ, c3, c4;
  if (isA) {
    loadW64(eWhh0, W1);
    #pragma unroll
    for (int s = 0; s < 3; s++) {
      const int n = (s * 4 + wvL) * 16 + c;
      #pragma unroll
      for (int kt = 0; kt < 2; kt++)
        #pragma unroll
        for (int j = 0; j < 8; j++) {
          float v = (kt == 0 && q == 0 && j < NIN) ? SC[s] * eWih0[n * NIN + j] : 0.0f;
          W2[s][kt][j] = (_Float16)v;
        }
    }
    cR = L2E * (ebih0[u] + ebhh0[u]);
    cZ = L2E * (ebih0[64 + u] + ebhh0[64 + u]);
    c3 = 2.0f * L2E * ebhh0[128 + u];   // gh const (src1 = Whh0)
    c4 = 2.0f * L2E * ebih0[128 + u];   // gi const (src2 = x)
  } else {
    loadW64(eWih1, W1); loadW64(eWhh1, W2);
    cR = L2E * (ebih1[u] + ebhh1[u]);
    cZ = L2E * (ebih1[64 + u] + ebhh1[64 + u]);
    c3 = 2.0f * L2E * ebih1[128 + u];   // gi const (src1 = Wih1)
    c4 = 2.0f * L2E * ebhh1[128 + u];   // gh const (src2 = Whh1)
  }
  __syncthreads();   // last barrier: everything after uses the flag protocol

  if (isA) {
    floatx4 QR = {cR, cR, cR, cR}, QZ = {cZ, cZ, cZ, cZ};
    floatx4 Q3 = {c3, c3, c3, c3}, Q4 = {c4, c4, c4, c4};
    // ---- x prefetch pipeline on wave A0, lanes 0..47, 2 slots each, depth 2 ----
    const bool doX = (wvL == 0) && (lane < 48);
    const float *px0 = nullptr, *px1 = nullptr;
    int xo0 = 0, xo1 = 0; float xn0 = 0.f, xn1 = 0.f;
    if (doX) {
      int s0_ = lane, s1_ = lane + 48;
      int m0 = s0_ / 6, i0 = s0_ - m0 * 6, m1 = s1_ / 6, i1 = s1_ - m1 * 6;
      px0 = x + (base + m0) * (TSEQ * NIN) + i0;
      px1 = x + (base + m1) * (TSEQ * NIN) + i1;
      xo0 = m0 * RS0 + 64 + i0; xo1 = m1 * RS0 + 64 + i1;
      xn0 = px0[NIN]; xn1 = px1[NIN];   // x(1)
    }
    // ================= encoder =================
    for (int i = 0; i < TSEQ; i += 2) {
      #pragma unroll
      for (int h2 = 0; h2 < 2; h2++) {
        const int i_ = i + h2, p = h2, pn = h2 ^ 1;
        pollge1(asum, 4u * (uint)i_);                  // peers done step i_-1 (incl. x(i_))
        const half8 a0 = ldh8(&s0[p][c][q * 8]);
        const half8 a1 = ldh8(&s0[p][c][32 + q * 8]);
        const half8 xf = ldh8(&s0[p][c][64 + q * 8]);
        floatx4 aR, aZ, a3, a4;
        PASS2_I3(a0, a1, aR, aZ, a3, W1, QR, QZ, Q3);  // Whh0.h0 -> gh
        PASS1_A2I1(xf, aR, aZ, a4, W2, Q4);            // Wih0.x  -> gi
        pollge1(bsum, 4u * (uint)(i_ > 0 ? i_ - 1 : 0));  // WAR: B consumed s0[pn] gen-2
        if (doX && i_ + 1 < TSEQ) {
          ((_Float16*)s0[pn])[xo0] = (_Float16)xn0;
          ((_Float16*)s0[pn])[xo1] = (_Float16)xn1;
          if (i_ + 2 < TSEQ) { xn0 = px0[(i_ + 2) * NIN]; xn1 = px1[(i_ + 2) * NIN]; }
        }
        #pragma unroll
        for (int r4 = 0; r4 < 4; r4++) {
          const float gr = sigm2(aR[r4]);
          const float gz = sigm2(aZ[r4]);
          const float nn = tanh2(a4[r4] + gr * a3[r4]);
          const float hn = nn + gz * (hr[r4] - nn);
          hr[r4] = hn;
          s0[pn][q * 4 + r4][u] = (_Float16)hn;
        }
        PUBLISH();
      }
    }
    // ================= decoder weights (fold) =================
    loadW64(dWhh0, W1);
    const float ob = outB[0];
    #pragma unroll
    for (int s = 0; s < 3; s++) {
      const int n = (s * 4 + wvL) * 16 + c;
      const float wd = SC[s] * dWih0[n];
      #pragma unroll
      for (int kt = 0; kt < 2; kt++) {
        const int k0 = kt * 32 + q * 8;
        #pragma unroll
        for (int j = 0; j < 8; j++) W2[s][kt][j] = (_Float16)(wd * outW[k0 + j]);
      }
    }
    const float bR0 = L2E * (dbih0[u] + dbhh0[u]);
    const float bZ0 = L2E * (dbih0[64 + u] + dbhh0[64 + u]);
    const float b30 = 2.0f * L2E * dbhh0[128 + u];
    const float b40 = 2.0f * L2E * dbih0[128 + u];
    cR = bR0 + L2E * (dWih0[u] * ob);
    cZ = bZ0 + L2E * (dWih0[64 + u] * ob);
    c3 = b30;
    c4 = b40 + 2.0f * L2E * (dWih0[128 + u] * ob);
    QR = (floatx4){cR, cR, cR, cR}; QZ = (floatx4){cZ, cZ, cZ, cZ};
    Q3 = (floatx4){c3, c3, c3, c3}; Q4 = (floatx4){c4, c4, c4, c4};
    // ---- peeled decoder step 256 (prev = 0: base biases, no fold) ----
    {
      pollge1(asum, 4u * (uint)TSEQ);
      const half8 a0 = ldh8(&s0[0][c][q * 8]);
      const half8 a1 = ldh8(&s0[0][c][32 + q * 8]);
      const floatx4 TR = {bR0, bR0, bR0, bR0}, TZ = {bZ0, bZ0, bZ0, bZ0};
      const floatx4 T3 = {b30, b30, b30, b30};
      floatx4 aR, aZ, a3;
      floatx4 a4 = {b40, b40, b40, b40};
      PASS2_I3(a0, a1, aR, aZ, a3, W1, TR, TZ, T3);
      pollge1(bsum, 4u * (uint)(TSEQ - 1));
      #pragma unroll
      for (int r4 = 0; r4 < 4; r4++) {
        const float gr = sigm2(aR[r4]);
        const float gz = sigm2(aZ[r4]);
        const float nn = tanh2(a4[r4] + gr * a3[r4]);
        const float hn = nn + gz * (hr[r4] - nn);
        hr[r4] = hn;
        s0[1][q * 4 + r4][u] = (_Float16)hn;
      }
      PUBLISH();
    }
    // ---- peeled decoder step 257 (p=1, pn=0; steady-state body) ----
    {
      pollge1(asum, 4u * (uint)(TSEQ + 1));
      const half8 a0 = ldh8(&s0[1][c][q * 8]);
      const half8 a1 = ldh8(&s0[1][c][32 + q * 8]);
      floatx4 aR, aZ, a3, a4;
      PASS2_I3(a0, a1, aR, aZ, a3, W1, QR, QZ, Q3);
      pollge1(bsum, 4u * (uint)(TSEQ + 1));
      const half8 b0 = ldh8(&s1[1][c][q * 8]);
      const half8 b1 = ldh8(&s1[1][c][32 + q * 8]);
      PASS2_A2I1(b0, b1, aR, aZ, a4, W2, Q4);
      #pragma unroll
      for (int r4 = 0; r4 < 4; r4++) {
        const float gr = sigm2(aR[r4]);
        const float gz = sigm2(aZ[r4]);
        const float nn = tanh2(a4[r4] + gr * a3[r4]);
        const float hn = nn + gz * (hr[r4] - nn);
        hr[r4] = hn;
        s0[0][q * 4 + r4][u] = (_Float16)hn;
      }
      PUBLISH();
    }
    // ---- steady decoder: steps 258..435, 89 pairs ----
    for (int i = TSEQ + 2; i < TSEQ + TDEC; i += 2) {
      #pragma unroll
      for (int h2 = 0; h2 < 2; h2++) {
        const int i_ = i + h2, p = h2, pn = h2 ^ 1;
        pollge1(asum, 4u * (uint)i_);
        const half8 a0 = ldh8(&s0[p][c][q * 8]);
        const half8 a1 = ldh8(&s0[p][c][32 + q * 8]);
        floatx4 aR, aZ, a3, a4;
        PASS2_I3(a0, a1, aR, aZ, a3, W1, QR, QZ, Q3);  // Whh0.h0 -> gh
        pollge1(bsum, 4u * (uint)i_);
        const half8 b0 = ldh8(&s1[p][c][q * 8]);       // rank-1 head fold: W'.h1(d-1)
        const half8 b1 = ldh8(&s1[p][c][32 + q * 8]);
        PASS2_A2I1(b0, b1, aR, aZ, a4, W2, Q4);
        #pragma unroll
        for (int r4 = 0; r4 < 4; r4++) {
          const float gr = sigm2(aR[r4]);
          const float gz = sigm2(aZ[r4]);
          const float nn = tanh2(a4[r4] + gr * a3[r4]);
          const float hn = nn + gz * (hr[r4] - nn);
          hr[r4] = hn;
          s0[pn][q * 4 + r4][u] = (_Float16)hn;
        }
        PUBLISH();
      }
    }
  } else {
    // =========================== group B: layer 1 ===========================
    floatx4 QR = {cR, cR, cR, cR}, QZ = {cZ, cZ, cZ, cZ};
    floatx4 Q3 = {c3, c3, c3, c3}, Q4 = {c4, c4, c4, c4};
    const float ob = outB[0];
    float wk[2][8];
    #pragma unroll
    for (int kt = 0; kt < 2; kt++)
      #pragma unroll
      for (int j = 0; j < 8; j++) wk[kt][j] = outW[kt * 32 + q * 8 + j];

    for (int i = 0; i < TSEQ; i += 2) {
      #pragma unroll
      for (int h2 = 0; h2 < 2; h2++) {
        const int i_ = i + h2, p = h2, pn = h2 ^ 1;
        pollge1(bsum, 4u * (uint)i_);                  // peers' h1(i_-1)
        const half8 f0 = ldh8(&s1[p][c][q * 8]);
        const half8 f1 = ldh8(&s1[p][c][32 + q * 8]);
        floatx4 aR, aZ, a3, a4;
        PASS2_I3(f0, f1, aR, aZ, a4, W2, QR, QZ, Q4);  // Whh1.h1 -> gh
        pollge1(asum, 4u * (uint)(i_ + 1));            // h0(i_) ready
        const half8 g0 = ldh8(&s0[pn][c][q * 8]);
        const half8 g1 = ldh8(&s0[pn][c][32 + q * 8]);
        PASS2_A2I1(g0, g1, aR, aZ, a3, W1, Q3);        // Wih1.h0 -> gi
        #pragma unroll
        for (int r4 = 0; r4 < 4; r4++) {
          const float gr = sigm2(aR[r4]);
          const float gz = sigm2(aZ[r4]);
          const float nn = tanh2(a3[r4] + gr * a4[r4]);
          const float hn = nn + gz * (hr[r4] - nn);
          hr[r4] = hn;
          s1[pn][q * 4 + r4][u] = (_Float16)hn;
        }
        PUBLISH();
      }
    }
    loadW64(dWih1, W1); loadW64(dWhh1, W2);
    cR = L2E * (dbih1[u] + dbhh1[u]);
    cZ = L2E * (dbih1[64 + u] + dbhh1[64 + u]);
    c3 = 2.0f * L2E * dbih1[128 + u];
    c4 = 2.0f * L2E * dbhh1[128 + u];
    QR = (floatx4){cR, cR, cR, cR}; QZ = (floatx4){cZ, cZ, cZ, cZ};
    Q3 = (floatx4){c3, c3, c3, c3}; Q4 = (floatx4){c4, c4, c4, c4};
    for (int i = TSEQ; i < TSEQ + TDEC; i += 2) {
      #pragma unroll
      for (int h2 = 0; h2 < 2; h2++) {
        const int i_ = i + h2, p = h2, pn = h2 ^ 1;
        pollge1(bsum, 4u * (uint)i_);
        const half8 f0 = ldh8(&s1[p][c][q * 8]);
        const half8 f1 = ldh8(&s1[p][c][32 + q * 8]);
        floatx4 aR, aZ, a3, a4;
        PASS2_I3(f0, f1, aR, aZ, a4, W2, QR, QZ, Q4);  // Whh1.h1 -> gh
        if (wvL == 0 && i_ > TSEQ) {   // head: cv(d) from h1(i_-1) fragments (off critical path)
          float cv = 0.0f;
          #pragma unroll
          for (int j = 0; j < 8; j++) {
            cv = fmaf((float)f0[j], wk[0][j], cv);
            cv = fmaf((float)f1[j], wk[1][j], cv);
          }
          cv += __shfl_xor(cv, 16);
          cv += __shfl_xor(cv, 32);
          if (lane < 16) out[(base + lane) * TDEC + (i_ - TSEQ - 1)] = cv + ob;
        }
        pollge1(asum, 4u * (uint)(i_ + 1));
        const half8 g0 = ldh8(&s0[pn][c][q * 8]);
        const half8 g1 = ldh8(&s0[pn][c][32 + q * 8]);
        PASS2_A2I1(g0, g1, aR, aZ, a3, W1, Q3);        // Wih1.h0 -> gi
        #pragma unroll
        for (int r4 = 0; r4 < 4; r4++) {
          const float gr = sigm2(aR[r4]);
          const float gz = sigm2(aZ[r4]);
          const float nn = tanh2(a3[r4] + gr * a4[r4]);
          const float hn = nn + gz * (hr[r4] - nn);
          hr[r4] = hn;
          s1[pn][q * 4 + r4][u] = (_Float16)hn;
        }
        PUBLISH();
      }
    }
    // final head value: cv(179) from h1(435) in s1[0]
    if (wvL == 0) {
      pollge1(bsum, 4u * (uint)(TSEQ + TDEC));
      const half8 f0 = ldh8(&s1[0][c][q * 8]);
      const half8 f1 = ldh8(&s1[0][c][32 + q * 8]);
      float cv = 0.0f;
      #pragma unroll
      for (int j = 0; j < 8; j++) {
        cv = fmaf((float)f0[j], wk[0][j], cv);
        cv = fmaf((float)f1[j], wk[1][j], cv);
      }
      cv += __shfl_xor(cv, 16);
      cv += __shfl_xor(cv, 32);
      if (lane < 16) out[(base + lane) * TDEC + (TDEC - 1)] = cv + ob;
    }
  }
}

extern "C" void kernel_launch(void* const* d_in, const int* in_sizes, int n_in,
                              void* d_out, int out_size, void* d_ws, size_t ws_size,
                              hipStream_t stream) {
  (void)in_sizes; (void)n_in; (void)d_ws; (void)ws_size; (void)out_size;
  const float* x     = (const float*)d_in[0];
  const float* eWih0 = (const float*)d_in[1];
  const float* eWhh0 = (const float*)d_in[2];
  const float* ebih0 = (const float*)d_in[3];
  const float* ebhh0 = (const float*)d_in[4];
  const float* eWih1 = (const float*)d_in[5];
  const float* eWhh1 = (const float*)d_in[6];
  const float* ebih1 = (const float*)d_in[7];
  const float* ebhh1 = (const float*)d_in[8];
  const float* dWih0 = (const float*)d_in[9];
  const float* dWhh0 = (const float*)d_in[10];
  const float* dbih0 = (const float*)d_in[11];
  const float* dbhh0 = (const float*)d_in[12];
  const float* dWih1 = (const float*)d_in[13];
  const float* dWhh1 = (const float*)d_in[14];
  const float* dbih1 = (const float*)d_in[15];
  const float* dbhh1 = (const float*)d_in[16];
  const float* outW  = (const float*)d_in[17];
  const float* outB  = (const float*)d_in[18];
  hipLaunchKernelGGL(gru_persist, dim3(NBLK), dim3(512), 0, stream,
                     x, eWih0, eWhh0, ebih0, ebhh0, eWih1, eWhh1, ebih1, ebhh1,
                     dWih0, dWhh0, dbih0, dbhh0, dWih1, dWhh1, dbih1, dbhh1,
                     outW, outB, (float*)d_out);
}

// Round 11
// 387.072 us; speedup vs baseline: 1.6707x; 1.0144x over previous
//
#include <hip/hip_runtime.h>
#include <cstdint>

typedef _Float16 half8 __attribute__((ext_vector_type(8)));
typedef __attribute__((ext_vector_type(4))) float floatx4;
typedef unsigned int uint;

#define TSEQ 256
#define TDEC 180
#define NIN  6
#define GROWS 16
#define NBLK (4096 / GROWS)
#define NSL 4     // state buffer depth: h(j) lives in slot (j+1)&3
#define RS0 104   // s0 row stride (halfs): cols 0..63 h0, 64..95 x|0, 96..103 pad
#define RS1 72    // s1 row stride
#define L2E 1.4426950408889634f

__device__ __forceinline__ floatx4 mfma16(half8 a, half8 b, floatx4 c) {
  return __builtin_amdgcn_mfma_f32_16x16x32_f16(a, b, c, 0, 0, 0);
}

// pre-scaled transcendentals: inputs already carry log2e (sigm) / 2*log2e (tanh)
__device__ __forceinline__ float sigm2(float v) {
  return __builtin_amdgcn_rcpf(1.0f + __builtin_amdgcn_exp2f(-v));
}
__device__ __forceinline__ float tanh2(float v) {
  return fmaf(2.0f, __builtin_amdgcn_rcpf(1.0f + __builtin_amdgcn_exp2f(-v)), -1.0f);
}

__device__ __forceinline__ half8 ldh8(const _Float16* p) { return *(const half8*)p; }

#define PASS2_I3(F0, F1, r, z, g, W, QR, QZ, QG) do {                   \
  r = mfma16(F0, W[0][0], QR); z = mfma16(F0, W[1][0], QZ); g = mfma16(F0, W[2][0], QG); \
  r = mfma16(F1, W[0][1], r);  z = mfma16(F1, W[1][1], z);  g = mfma16(F1, W[2][1], g);  \
} while (0)

#define PASS2_A2I1(F0, F1, r, z, g, W, QG) do {                         \
  r = mfma16(F0, W[0][0], r); z = mfma16(F0, W[1][0], z); g = mfma16(F0, W[2][0], QG); \
  r = mfma16(F1, W[0][1], r); z = mfma16(F1, W[1][1], z); g = mfma16(F1, W[2][1], g);  \
} while (0)

#define PASS1_A2I1(F0, r, z, g, W, QG) do {                             \
  r = mfma16(F0, W[0][0], r); z = mfma16(F0, W[1][0], z); g = mfma16(F0, W[2][0], QG); \
} while (0)

// sum-counter poll: all 4 waves of a group finished >= n  <=>  sum >= 4n
__device__ __forceinline__ void pollge1(const volatile uint* p, uint need4) {
  for (;;) {
    if (*p >= need4) break;
    __builtin_amdgcn_s_sleep(1);
  }
  asm volatile("" ::: "memory");
}

// DS ops of one wave execute in order: ds_add publish cannot pass prior ds_writes.
#define PUBLISH() do { asm volatile("" ::: "memory"); if (lane == 0) atomicAdd(mysum, 1u); } while (0)

__global__ void __launch_bounds__(512, 2)
gru_persist(const float* __restrict__ x,
            const float* __restrict__ eWih0, const float* __restrict__ eWhh0,
            const float* __restrict__ ebih0, const float* __restrict__ ebhh0,
            const float* __restrict__ eWih1, const float* __restrict__ eWhh1,
            const float* __restrict__ ebih1, const float* __restrict__ ebhh1,
            const float* __restrict__ dWih0, const float* __restrict__ dWhh0,
            const float* __restrict__ dbih0, const float* __restrict__ dbhh0,
            const float* __restrict__ dWih1, const float* __restrict__ dWhh1,
            const float* __restrict__ dbih1, const float* __restrict__ dbhh1,
            const float* __restrict__ outW, const float* __restrict__ outB,
            float* __restrict__ out)
{
  __shared__ __align__(16) _Float16 s0[NSL][16][RS0];
  __shared__ __align__(16) _Float16 s1[NSL][16][RS1];
  __shared__ __align__(16) uint prog[16];   // prog[0]=A-sum, prog[8]=B-sum

  const int tid  = threadIdx.x;
  const bool isA = tid < 256;          // A = layer0 waves, B = layer1 waves
  const int wvL  = (tid >> 6) & 3;
  const int lane = tid & 63;
  const int c    = lane & 15;
  const int q    = lane >> 4;
  const int u    = wvL * 16 + c;
  const long base = (long)blockIdx.x * GROWS;

  const volatile uint* asum = (const volatile uint*)&prog[0];
  const volatile uint* bsum = (const volatile uint*)&prog[8];
  uint* mysum = (uint*)&prog[isA ? 0 : 8];

  for (int i = tid; i < NSL * 16 * RS0; i += 512) ((uint16_t*)s0)[i] = 0;
  for (int i = tid; i < NSL * 16 * RS1; i += 512) ((uint16_t*)s1)[i] = 0;
  if (tid < 16) prog[tid] = 0;
  if (tid < GROWS * NIN) {  // x(0) -> s0[0]
    int m = tid / 6, i2 = tid - m * 6;
    s0[0][m][64 + i2] = (_Float16)x[(base + m) * (TSEQ * NIN) + i2];
  }

  // encoder + decoder weights ALL register-resident from the start (no mid-kernel loads)
  half8 W1[3][2], W2[3][2];    // encoder: A: Whh0 / [Wih0|0] | B: Wih1 / Whh1
  half8 W1d[3][2], W2d[3][2];  // decoder: A: Whh0d / rank-1 fold | B: Wih1d / Whh1d
  float hr[4] = {0, 0, 0, 0};
  const float SC[3] = {L2E, L2E, 2.0f * L2E};   // r, z, n row scales (fold exp2 args)

  auto loadW64 = [&](const float* W, half8 (&D)[3][2]) {
    #pragma unroll
    for (int s = 0; s < 3; s++) {
      const int n = (s * 4 + wvL) * 16 + c;
      #pragma unroll
      for (int kt = 0; kt < 2; kt++) {
        const int k0 = kt * 32 + q * 8;
        #pragma unroll
        for (int j = 0; j < 8; j++) D[s][kt][j] = (_Float16)(SC[s] * W[n * 64 + k0 + j]);
      }
    }
  };

  const float ob = outB[0];
  float cR, cZ, c3, c4;          // encoder consts
  float dR, dZ, d3, d4;          // decoder steady consts
  float bR0 = 0, bZ0 = 0, b30 = 0, b40 = 0;   // A decoder first-step consts
  float wk[2][8];                // B: head weights
  if (isA) {
    loadW64(eWhh0, W1);
    #pragma unroll
    for (int s = 0; s < 3; s++) {
      const int n = (s * 4 + wvL) * 16 + c;
      #pragma unroll
      for (int kt = 0; kt < 2; kt++)
        #pragma unroll
        for (int j = 0; j < 8; j++) {
          float v = (kt == 0 && q == 0 && j < NIN) ? SC[s] * eWih0[n * NIN + j] : 0.0f;
          W2[s][kt][j] = (_Float16)v;
        }
    }
    loadW64(dWhh0, W1d);
    #pragma unroll
    for (int s = 0; s < 3; s++) {   // W2d = rank-1 head fold: SC[s] * dWih0[n] * outW[k]
      const int n = (s * 4 + wvL) * 16 + c;
      const float wd = SC[s] * dWih0[n];
      #pragma unroll
      for (int kt = 0; kt < 2; kt++) {
        const int k0 = kt * 32 + q * 8;
        #pragma unroll
        for (int j = 0; j < 8; j++) W2d[s][kt][j] = (_Float16)(wd * outW[k0 + j]);
      }
    }
    cR = L2E * (ebih0[u] + ebhh0[u]);
    cZ = L2E * (ebih0[64 + u] + ebhh0[64 + u]);
    c3 = 2.0f * L2E * ebhh0[128 + u];   // gh const
    c4 = 2.0f * L2E * ebih0[128 + u];   // gi const
    bR0 = L2E * (dbih0[u] + dbhh0[u]);
    bZ0 = L2E * (dbih0[64 + u] + dbhh0[64 + u]);
    b30 = 2.0f * L2E * dbhh0[128 + u];
    b40 = 2.0f * L2E * dbih0[128 + u];
    dR = bR0 + L2E * (dWih0[u] * ob);
    dZ = bZ0 + L2E * (dWih0[64 + u] * ob);
    d3 = b30;
    d4 = b40 + 2.0f * L2E * (dWih0[128 + u] * ob);
  } else {
    loadW64(eWih1, W1); loadW64(eWhh1, W2);
    loadW64(dWih1, W1d); loadW64(dWhh1, W2d);
    cR = L2E * (ebih1[u] + ebhh1[u]);
    cZ = L2E * (ebih1[64 + u] + ebhh1[64 + u]);
    c3 = 2.0f * L2E * ebih1[128 + u];   // gi const
    c4 = 2.0f * L2E * ebhh1[128 + u];   // gh const
    dR = L2E * (dbih1[u] + dbhh1[u]);
    dZ = L2E * (dbih1[64 + u] + dbhh1[64 + u]);
    d3 = 2.0f * L2E * dbih1[128 + u];
    d4 = 2.0f * L2E * dbhh1[128 + u];
    #pragma unroll
    for (int kt = 0; kt < 2; kt++)
      #pragma unroll
      for (int j = 0; j < 8; j++) wk[kt][j] = outW[kt * 32 + q * 8 + j];
  }
  __syncthreads();   // last barrier: everything after uses the flag protocol

  if (isA) {
    floatx4 QR = {cR, cR, cR, cR}, QZ = {cZ, cZ, cZ, cZ};
    floatx4 Q3 = {c3, c3, c3, c3}, Q4 = {c4, c4, c4, c4};
    // ---- x prefetch, wave A0, lanes 0..47, 2 slots each, depth 2 ----
    const bool doX = (wvL == 0) && (lane < 48);
    const float *px0 = nullptr, *px1 = nullptr;
    int xo0 = 0, xo1 = 0;
    float xa0 = 0.f, xa1 = 0.f, xb0 = 0.f, xb1 = 0.f;   // (xa=next-to-write, xb=following)
    if (doX) {
      int s0_ = lane, s1_ = lane + 48;
      int m0 = s0_ / 6, i0 = s0_ - m0 * 6, m1 = s1_ / 6, i1 = s1_ - m1 * 6;
      px0 = x + (base + m0) * (TSEQ * NIN) + i0;
      px1 = x + (base + m1) * (TSEQ * NIN) + i1;
      xo0 = m0 * RS0 + 64 + i0; xo1 = m1 * RS0 + 64 + i1;
      xa0 = px0[NIN];     xa1 = px1[NIN];       // x(1)
      xb0 = px0[2 * NIN]; xb1 = px1[2 * NIN];   // x(2)
    }
    // ================= encoder: A free-runs up to 3 ahead of B =================
    for (int i = 0; i < TSEQ; i += 4) {
      #pragma unroll
      for (int h4 = 0; h4 < 4; h4++) {
        const int i_ = i + h4, p = h4, pn = (h4 + 1) & 3;
        pollge1(asum, 4u * (uint)i_);                  // A peers done step i_-1
        const half8 a0 = ldh8(&s0[p][c][q * 8]);
        const half8 a1 = ldh8(&s0[p][c][32 + q * 8]);
        const half8 xf = ldh8(&s0[p][c][64 + q * 8]);
        floatx4 aR, aZ, a3, a4;
        PASS2_I3(a0, a1, aR, aZ, a3, W1, QR, QZ, Q3);  // Whh0.h0 -> gh
        PASS1_A2I1(xf, aR, aZ, a4, W2, Q4);            // Wih0.x  -> gi
        pollge1(bsum, 4u * (uint)(i_ > 3 ? i_ - 3 : 0));   // WAR: slot gen-4 consumed
        if (doX && i_ + 1 < TSEQ) {
          ((_Float16*)s0[pn])[xo0] = (_Float16)xa0;
          ((_Float16*)s0[pn])[xo1] = (_Float16)xa1;
          xa0 = xb0; xa1 = xb1;
          if (i_ + 3 < TSEQ) { xb0 = px0[(i_ + 3) * NIN]; xb1 = px1[(i_ + 3) * NIN]; }
        }
        #pragma unroll
        for (int r4 = 0; r4 < 4; r4++) {
          const float gr = sigm2(aR[r4]);
          const float gz = sigm2(aZ[r4]);
          const float nn = tanh2(a4[r4] + gr * a3[r4]);
          const float hn = nn + gz * (hr[r4] - nn);
          hr[r4] = hn;
          s0[pn][q * 4 + r4][u] = (_Float16)hn;
        }
        PUBLISH();
      }
    }
    // ================= decoder (strict A<->B cycle, weights preloaded) =================
    QR = (floatx4){dR, dR, dR, dR}; QZ = (floatx4){dZ, dZ, dZ, dZ};
    Q3 = (floatx4){d3, d3, d3, d3}; Q4 = (floatx4){d4, d4, d4, d4};
    // ---- peeled step 256 (prev = 0: base biases, no fold); slots p=0, pn=1 ----
    {
      pollge1(asum, 4u * (uint)TSEQ);
      const half8 a0 = ldh8(&s0[0][c][q * 8]);
      const half8 a1 = ldh8(&s0[0][c][32 + q * 8]);
      const floatx4 TR = {bR0, bR0, bR0, bR0}, TZ = {bZ0, bZ0, bZ0, bZ0};
      const floatx4 T3 = {b30, b30, b30, b30};
      floatx4 aR, aZ, a3;
      floatx4 a4 = {b40, b40, b40, b40};
      PASS2_I3(a0, a1, aR, aZ, a3, W1d, TR, TZ, T3);
      pollge1(bsum, 4u * (uint)(TSEQ - 1));
      #pragma unroll
      for (int r4 = 0; r4 < 4; r4++) {
        const float gr = sigm2(aR[r4]);
        const float gz = sigm2(aZ[r4]);
        const float nn = tanh2(a4[r4] + gr * a3[r4]);
        const float hn = nn + gz * (hr[r4] - nn);
        hr[r4] = hn;
        s0[1][q * 4 + r4][u] = (_Float16)hn;
      }
      PUBLISH();
    }
    // ---- steady: steps 257..435, dynamic slots ----
    for (int i_ = TSEQ + 1; i_ < TSEQ + TDEC; i_++) {
      const int p = i_ & 3, pn = (i_ + 1) & 3;
      pollge1(asum, 4u * (uint)i_);
      const half8 a0 = ldh8(&s0[p][c][q * 8]);
      const half8 a1 = ldh8(&s0[p][c][32 + q * 8]);
      floatx4 aR, aZ, a3, a4;
      PASS2_I3(a0, a1, aR, aZ, a3, W1d, QR, QZ, Q3);   // Whh0.h0 -> gh
      pollge1(bsum, 4u * (uint)i_);
      const half8 b0 = ldh8(&s1[p][c][q * 8]);         // rank-1 head fold: W'.h1(d-1)
      const half8 b1 = ldh8(&s1[p][c][32 + q * 8]);
      PASS2_A2I1(b0, b1, aR, aZ, a4, W2d, Q4);
      #pragma unroll
      for (int r4 = 0; r4 < 4; r4++) {
        const float gr = sigm2(aR[r4]);
        const float gz = sigm2(aZ[r4]);
        const float nn = tanh2(a4[r4] + gr * a3[r4]);
        const float hn = nn + gz * (hr[r4] - nn);
        hr[r4] = hn;
        s0[pn][q * 4 + r4][u] = (_Float16)hn;
      }
      PUBLISH();
    }
  } else {
    // =========================== group B: layer 1 ===========================
    floatx4 QR = {cR, cR, cR, cR}, QZ = {cZ, cZ, cZ, cZ};
    floatx4 Q3 = {c3, c3, c3, c3}, Q4 = {c4, c4, c4, c4};
    for (int i = 0; i < TSEQ; i += 4) {
      #pragma unroll
      for (int h4 = 0; h4 < 4; h4++) {
        const int i_ = i + h4, p = h4, pn = (h4 + 1) & 3;
        pollge1(bsum, 4u * (uint)i_);                  // B peers done step i_-1
        const half8 f0 = ldh8(&s1[p][c][q * 8]);
        const half8 f1 = ldh8(&s1[p][c][32 + q * 8]);
        floatx4 aR, aZ, a3, a4;
        PASS2_I3(f0, f1, aR, aZ, a4, W2, QR, QZ, Q4);  // Whh1.h1 -> gh
        pollge1(asum, 4u * (uint)(i_ + 1));            // h0(i_) ready in s0[pn]
        const half8 g0 = ldh8(&s0[pn][c][q * 8]);
        const half8 g1 = ldh8(&s0[pn][c][32 + q * 8]);
        PASS2_A2I1(g0, g1, aR, aZ, a3, W1, Q3);        // Wih1.h0 -> gi
        #pragma unroll
        for (int r4 = 0; r4 < 4; r4++) {
          const float gr = sigm2(aR[r4]);
          const float gz = sigm2(aZ[r4]);
          const float nn = tanh2(a3[r4] + gr * a4[r4]);
          const float hn = nn + gz * (hr[r4] - nn);
          hr[r4] = hn;
          s1[pn][q * 4 + r4][u] = (_Float16)hn;
        }
        PUBLISH();
      }
    }
    QR = (floatx4){dR, dR, dR, dR}; QZ = (floatx4){dZ, dZ, dZ, dZ};
    Q3 = (floatx4){d3, d3, d3, d3}; Q4 = (floatx4){d4, d4, d4, d4};
    for (int i_ = TSEQ; i_ < TSEQ + TDEC; i_++) {
      const int p = i_ & 3, pn = (i_ + 1) & 3;
      pollge1(bsum, 4u * (uint)i_);
      const half8 f0 = ldh8(&s1[p][c][q * 8]);
      const half8 f1 = ldh8(&s1[p][c][32 + q * 8]);
      floatx4 aR, aZ, a3, a4;
      PASS2_I3(f0, f1, aR, aZ, a4, W2d, QR, QZ, Q4);   // Whh1.h1 -> gh
      if (wvL == 0 && i_ > TSEQ) {   // head: cv from h1(i_-1) fragments (off critical path)
        float cv = 0.0f;
        #pragma unroll
        for (int j = 0; j < 8; j++) {
          cv = fmaf((float)f0[j], wk[0][j], cv);
          cv = fmaf((float)f1[j], wk[1][j], cv);
        }
        cv += __shfl_xor(cv, 16);
        cv += __shfl_xor(cv, 32);
        if (lane < 16) out[(base + lane) * TDEC + (i_ - TSEQ - 1)] = cv + ob;
      }
      pollge1(asum, 4u * (uint)(i_ + 1));
      const half8 g0 = ldh8(&s0[pn][c][q * 8]);
      const half8 g1 = ldh8(&s0[pn][c][32 + q * 8]);
      PASS2_A2I1(g0, g1, aR, aZ, a3, W1d, Q3);         // Wih1.h0 -> gi
      #pragma unroll
      for (int r4 = 0; r4 < 4; r4++) {
        const float gr = sigm2(aR[r4]);
        const float gz = sigm2(aZ[r4]);
        const float nn = tanh2(a3[r4] + gr * a4[r4]);
        const float hn = nn + gz * (hr[r4] - nn);
        hr[r4] = hn;
        s1[pn][q * 4 + r4][u] = (_Float16)hn;
      }
      PUBLISH();
    }
    // final head value: cv(179) from h1(435) in s1[(436)&3 = 0]
    if (wvL == 0) {
      pollge1(bsum, 4u * (uint)(TSEQ + TDEC));
      const half8 f0 = ldh8(&s1[0][c][q * 8]);
      const half8 f1 = ldh8(&s1[0][c][32 + q * 8]);
      float cv = 0.0f;
      #pragma unroll
      for (int j = 0; j < 8; j++) {
        cv = fmaf((float)f0[j], wk[0][j], cv);
        cv = fmaf((float)f1[j], wk[1][j], cv);
      }
      cv += __shfl_xor(cv, 16);
      cv += __shfl_xor(cv, 32);
      if (lane < 16) out[(base + lane) * TDEC + (TDEC - 1)] = cv + ob;
    }
  }
}

extern "C" void kernel_launch(void* const* d_in, const int* in_sizes, int n_in,
                              void* d_out, int out_size, void* d_ws, size_t ws_size,
                              hipStream_t stream) {
  (void)in_sizes; (void)n_in; (void)d_ws; (void)ws_size; (void)out_size;
  const float* x     = (const float*)d_in[0];
  const float* eWih0 = (const float*)d_in[1];
  const float* eWhh0 = (const float*)d_in[2];
  const float* ebih0 = (const float*)d_in[3];
  const float* ebhh0 = (const float*)d_in[4];
  const float* eWih1 = (const float*)d_in[5];
  const float* eWhh1 = (const float*)d_in[6];
  const float* ebih1 = (const float*)d_in[7];
  const float* ebhh1 = (const float*)d_in[8];
  const float* dWih0 = (const float*)d_in[9];
  const float* dWhh0 = (const float*)d_in[10];
  const float* dbih0 = (const float*)d_in[11];
  const float* dbhh0 = (const float*)d_in[12];
  const float* dWih1 = (const float*)d_in[13];
  const float* dWhh1 = (const float*)d_in[14];
  const float* dbih1 = (const float*)d_in[15];
  const float* dbhh1 = (const float*)d_in[16];
  const float* outW  = (const float*)d_in[17];
  const float* outB  = (const float*)d_in[18];
  hipLaunchKernelGGL(gru_persist, dim3(NBLK), dim3(512), 0, stream,
                     x, eWih0, eWhh0, ebih0, ebhh0, eWih1, eWhh1, ebih1, ebhh1,
                     dWih0, dWhh0, dbih0, dbhh0, dWih1, dWhh1, dbih1, dbhh1,
                     outW, outB, (float*)d_out);
}